// Round 11
// baseline (304.141 us; speedup 1.0000x reference)
//
#include <hip/hip_runtime.h>

// AVWGCN: B=32, N=2048, C=64, O=64, K=3, D=16
// R11 changes vs R10 (gconv_mfma = #1 at 65us, all pipes idle: per-d barrier + compiler
// vmcnt(0) drain around the aliased LDS ping-pong serializes everything):
//  - gconv_mfma rewritten BARRIER-FREE: A-frags and B-frags loaded directly from global
//    into registers (A once — wave-uniform source branches, coalesced 16rows x 64-128B;
//    B per-d from L2-resident Wpb, 12 bf16x8/wave/d). No As/Bs LDS, no d-loop barriers;
//    compiler pipelines next-d loads under current-d MFMAs. El stays in LDS (8 KB,
//    broadcast ds_read_b128). launch_bounds(256,2) caps VGPR at 256 (est ~230).
// Rest identical to R10 (tiled ee + softmax_rows + 3 split-K GEMMs + reduces).
// Workspace (80 MiB):
//  [0,16M) Acat -> xg1b [0,8M)        [16,32M) sawb -> S_bf [16,24M) + xg1T [24,32M)
//  [32,40M) XtT   [40,40.4M) Wpb  [41,41.5M) bias
//  [48,80M): z fp32 [48,64M) (pre-softmax) -> 4x bf16 split-K partials (z, G1, G2)

typedef unsigned short u16;
typedef float f32x4 __attribute__((ext_vector_type(4)));
typedef __bf16 bf16x8 __attribute__((ext_vector_type(8)));
typedef unsigned short u16x8 __attribute__((ext_vector_type(8)));

#define PSTRIDE ((size_t)2048 * 2048)

__device__ __forceinline__ u16 f2bf(float f) {
    unsigned u = __float_as_uint(f);
    u += 0x7FFFu + ((u >> 16) & 1u);   // RNE
    return (u16)(u >> 16);
}
__device__ __forceinline__ float bf2f(u16 h) {
    return __uint_as_float((unsigned)h << 16);
}
__device__ __forceinline__ void gl_lds16(const void* g, void* l) {
    __builtin_amdgcn_global_load_lds(
        (const __attribute__((address_space(1))) unsigned*)g,
        (__attribute__((address_space(3))) unsigned*)l, 16, 0, 0);
}

// ---------------------------------------------------------------- preamble (fused)
// blocks [0,256): ee tile: z[r0:r0+256, c0:c0+64] = relu(E@E^T) fp32
// blocks [256,4352): adj cast -> Acat right half
// blocks [4352,12544): saw cast -> sawb
// blocks [12544,13568): x -> XtT[(b*64+c)][m] bf16
// blocks [13568,13648): prep Wpb + bias
__global__ __launch_bounds__(256)
void preamble(const float* __restrict__ E, const float* __restrict__ adj,
              const float* __restrict__ saw, const float* __restrict__ x,
              const float* __restrict__ Wp, const float* __restrict__ bp,
              float* __restrict__ zf, u16* __restrict__ Acat,
              u16* __restrict__ sawb, u16* __restrict__ xtT,
              u16* __restrict__ Wpb, float* __restrict__ bias) {
    __shared__ u16 t[64][65];
    __shared__ float Bp[1024];        // 64-row E panel (cols of z), 4 KB
    const int bid = blockIdx.x, tid = threadIdx.x;

    if (bid < 256) {
        const int c0 = (bid & 31) * 64, r0 = (bid >> 5) * 256;
        const int r = r0 + tid;
        const float4* Er = (const float4*)(E + (size_t)r * 16);
        float4 e0 = Er[0], e1 = Er[1], e2 = Er[2], e3 = Er[3];
        *(float4*)(Bp + tid * 4) = *(const float4*)(E + (size_t)c0 * 16 + tid * 4);
        __syncthreads();
        float* zr = zf + (size_t)r * 2048 + c0;
#pragma unroll
        for (int cc = 0; cc < 4; ++cc) {
            float acc[16];
#pragma unroll
            for (int c = 0; c < 16; ++c) {
                const float* bp2 = Bp + (cc * 16 + c) * 16;   // broadcast reads
                float s = 0.f;
                s = fmaf(e0.x, bp2[0], s);  s = fmaf(e0.y, bp2[1], s);
                s = fmaf(e0.z, bp2[2], s);  s = fmaf(e0.w, bp2[3], s);
                s = fmaf(e1.x, bp2[4], s);  s = fmaf(e1.y, bp2[5], s);
                s = fmaf(e1.z, bp2[6], s);  s = fmaf(e1.w, bp2[7], s);
                s = fmaf(e2.x, bp2[8], s);  s = fmaf(e2.y, bp2[9], s);
                s = fmaf(e2.z, bp2[10], s); s = fmaf(e2.w, bp2[11], s);
                s = fmaf(e3.x, bp2[12], s); s = fmaf(e3.y, bp2[13], s);
                s = fmaf(e3.z, bp2[14], s); s = fmaf(e3.w, bp2[15], s);
                acc[c] = fmaxf(s, 0.f);                      // relu
            }
#pragma unroll
            for (int q = 0; q < 4; ++q)
                *(float4*)(zr + cc * 16 + q * 4) =
                    make_float4(acc[q * 4], acc[q * 4 + 1], acc[q * 4 + 2], acc[q * 4 + 3]);
        }
    } else if (bid < 4352) {
        size_t j = ((size_t)(bid - 256) * 256 + tid) * 4;
        float4 v = *(const float4*)(adj + j);
        int n = (int)(j >> 11), c = (int)(j & 2047);
        ushort4 o = make_ushort4(f2bf(v.x), f2bf(v.y), f2bf(v.z), f2bf(v.w));
        *(ushort4*)(Acat + (size_t)n * 4096 + 2048 + c) = o;
    } else if (bid < 12544) {
        size_t j = ((size_t)(bid - 4352) * 256 + tid) * 4;
        float4 v = *(const float4*)(saw + j);
        ushort4 o = make_ushort4(f2bf(v.x), f2bf(v.y), f2bf(v.z), f2bf(v.w));
        *(ushort4*)(sawb + j) = o;
    } else if (bid < 13568) {
        int local = bid - 12544;
        int m0 = (local & 31) * 64, b = local >> 5;
        int c = tid & 63, g = tid >> 6;
#pragma unroll
        for (int r = 0; r < 16; ++r) {
            int mm = g * 16 + r;
            t[mm][c] = f2bf(x[((size_t)b * 2048 + m0 + mm) * 64 + c]);
        }
        __syncthreads();
#pragma unroll
        for (int r = 0; r < 16; ++r) {
            int cc = g * 16 + r;
            xtT[((size_t)b * 64 + cc) * 2048 + m0 + c] = t[c][cc];
        }
    } else {
        int local = bid - 13568;
        if (local < 16) {
            const int d = local;
            const float* base = Wp + (size_t)d * 12288;    // [k][i][o]
            for (int idx = tid; idx < 12288; idx += 256) {
                int o = idx / 192, ki = idx - o * 192;
                int k = ki >> 6, i = ki & 63;
                float v;
                if (k == 0)      v = base[i * 64 + o] - base[2 * 4096 + i * 64 + o];
                else if (k == 1) v = base[4096 + i * 64 + o];
                else             v = 2.f * base[2 * 4096 + i * 64 + o];
                Wpb[(size_t)(d * 64 + o) * 192 + ki] = f2bf(v);
            }
        } else {
            const int nb = local - 16;                     // 64 blocks x 32 n
#pragma unroll
            for (int it = 0; it < 8; ++it) {
                int idx = tid + it * 256;
                int n = nb * 32 + (idx >> 6), o = idx & 63;
                float s = 0.f;
#pragma unroll
                for (int d = 0; d < 16; ++d) s = fmaf(E[n * 16 + d], bp[d * 64 + o], s);
                bias[(size_t)n * 64 + o] = s;
            }
        }
    }
}

// ---------------------------------------------------------------- row softmax (z already relu'd)
__global__ __launch_bounds__(256)
void softmax_rows(const float* __restrict__ zf, u16* __restrict__ Acat) {
    __shared__ float red[4];
    const int n = blockIdx.x, tid = threadIdx.x;
    const int lane = tid & 63, wave = tid >> 6;
    const float* zr = zf + (size_t)n * 2048;
    float4 a = *(const float4*)(zr + tid * 8);
    float4 b = *(const float4*)(zr + tid * 8 + 4);
    float mx = fmaxf(fmaxf(fmaxf(a.x, a.y), fmaxf(a.z, a.w)),
                     fmaxf(fmaxf(b.x, b.y), fmaxf(b.z, b.w)));
    for (int off = 32; off; off >>= 1) mx = fmaxf(mx, __shfl_down(mx, off, 64));
    if (lane == 0) red[wave] = mx;
    __syncthreads();
    mx = fmaxf(fmaxf(red[0], red[1]), fmaxf(red[2], red[3]));
    __syncthreads();
    float v[8] = {__expf(a.x - mx), __expf(a.y - mx), __expf(a.z - mx), __expf(a.w - mx),
                  __expf(b.x - mx), __expf(b.y - mx), __expf(b.z - mx), __expf(b.w - mx)};
    float sum = v[0] + v[1] + v[2] + v[3] + v[4] + v[5] + v[6] + v[7];
    for (int off = 32; off; off >>= 1) sum += __shfl_down(sum, off, 64);
    if (lane == 0) red[wave] = sum;
    __syncthreads();
    sum = red[0] + red[1] + red[2] + red[3];
    float inv = 1.f / sum;
    u16* orow = Acat + (size_t)n * 4096 + tid * 8;
    *(ushort4*)orow = make_ushort4(f2bf(v[0] * inv), f2bf(v[1] * inv),
                                   f2bf(v[2] * inv), f2bf(v[3] * inv));
    *(ushort4*)(orow + 4) = make_ushort4(f2bf(v[4] * inv), f2bf(v[5] * inv),
                                         f2bf(v[6] * inv), f2bf(v[7] * inv));
}

// ---------------------------------------------------------------- GEMM 128x128, BK=64, split-K
// C[m,n] = sum_k A[m,k]*Bt[n,k]; bf16 partial -> Cp + z*M*N.
__global__ __launch_bounds__(256, 3)
void gemm_bt(const u16* __restrict__ A, const u16* __restrict__ Bt,
             u16* __restrict__ Cp, int M, int N, int K, int Kh) {
    __shared__ alignas(16) u16 As[128 * 64];   // 16 KB
    __shared__ alignas(16) u16 Bs[128 * 64];   // 16 KB
    const int tid = threadIdx.x, lane = tid & 63, wave = tid >> 6;
    const int m0 = blockIdx.y * 128, n0 = blockIdx.x * 128;
    const int wm = (wave >> 1) * 64, wn = (wave & 1) * 64;
    const int kbeg = blockIdx.z * Kh, kend = kbeg + Kh;
    const int ml = lane & 15, c0l = lane >> 4;
    f32x4 acc[4][4] = {};

    int baseA[4], mskA[4], baseB[4], mskB[4];
#pragma unroll
    for (int i = 0; i < 4; ++i) { int m = wm + i * 16 + ml; baseA[i] = m * 8; mskA[i] = m & 7; }
#pragma unroll
    for (int j = 0; j < 4; ++j) { int nn = wn + j * 16 + ml; baseB[j] = nn * 8; mskB[j] = nn & 7; }

    for (int k0 = kbeg; k0 < kend; k0 += 64) {
#pragma unroll
        for (int r = 0; r < 4; ++r) {           // A: 1024 16B-chunks
            int s = wave * 64 + r * 256 + lane;
            int row = s >> 3, gc = (s & 7) ^ (row & 7);
            gl_lds16(A + (size_t)(m0 + row) * K + k0 + gc * 8, As + (size_t)s * 8);
        }
#pragma unroll
        for (int r = 0; r < 4; ++r) {           // B: 1024 16B-chunks
            int s = wave * 64 + r * 256 + lane;
            int row = s >> 3, gc = (s & 7) ^ (row & 7);
            gl_lds16(Bt + (size_t)(n0 + row) * K + k0 + gc * 8, Bs + (size_t)s * 8);
        }
        __syncthreads();
#pragma unroll
        for (int ks4 = 0; ks4 < 8; ks4 += 4) {
            bf16x8 af[4], bv[4];
#pragma unroll
            for (int i = 0; i < 4; ++i)
                af[i] = *(const bf16x8*)(As + (baseA[i] + ((c0l + ks4) ^ mskA[i])) * 8);
#pragma unroll
            for (int j = 0; j < 4; ++j)
                bv[j] = *(const bf16x8*)(Bs + (baseB[j] + ((c0l + ks4) ^ mskB[j])) * 8);
#pragma unroll
            for (int i = 0; i < 4; ++i)
#pragma unroll
                for (int j = 0; j < 4; ++j)
                    acc[i][j] = __builtin_amdgcn_mfma_f32_16x16x32_bf16(af[i], bv[j], acc[i][j], 0, 0, 0);
        }
        __syncthreads();
    }

    const int col_l = lane & 15, row_l = (lane >> 4) * 4;
    u16* Cz = Cp + (size_t)blockIdx.z * M * N;
#pragma unroll
    for (int i = 0; i < 4; ++i)
#pragma unroll
        for (int j = 0; j < 4; ++j)
#pragma unroll
            for (int r = 0; r < 4; ++r) {
                int row = m0 + wm + i * 16 + row_l + r;
                int col = n0 + wn + j * 16 + col_l;
                Cz[(size_t)row * N + col] = f2bf(acc[i][j][r]);
            }
}

// ---------------------------------------------------------------- split-K reduces
// S = sig(z)*adj + (1-sig(z))*sup;  sup + adj both from Acat (bf16)
__global__ __launch_bounds__(256)
void reduce_z(const u16* __restrict__ p, const u16* __restrict__ Acat,
              u16* __restrict__ S) {
    size_t j = ((size_t)blockIdx.x * 256 + threadIdx.x) * 4;
    ushort4 p0 = *(const ushort4*)(p + j);
    ushort4 p1 = *(const ushort4*)(p + PSTRIDE + j);
    ushort4 p2 = *(const ushort4*)(p + 2 * PSTRIDE + j);
    ushort4 p3 = *(const ushort4*)(p + 3 * PSTRIDE + j);
    int row = (int)(j >> 11), col = (int)(j & 2047);
    ushort4 sp = *(const ushort4*)(Acat + (size_t)row * 4096 + col);
    ushort4 ad = *(const ushort4*)(Acat + (size_t)row * 4096 + 2048 + col);
    float z0 = bf2f(p0.x) + bf2f(p1.x) + bf2f(p2.x) + bf2f(p3.x);
    float z1 = bf2f(p0.y) + bf2f(p1.y) + bf2f(p2.y) + bf2f(p3.y);
    float z2 = bf2f(p0.z) + bf2f(p1.z) + bf2f(p2.z) + bf2f(p3.z);
    float z3 = bf2f(p0.w) + bf2f(p1.w) + bf2f(p2.w) + bf2f(p3.w);
    float s0 = 1.f / (1.f + __expf(-z0)), s1 = 1.f / (1.f + __expf(-z1));
    float s2 = 1.f / (1.f + __expf(-z2)), s3 = 1.f / (1.f + __expf(-z3));
    ushort4 o = make_ushort4(
        f2bf(s0 * bf2f(ad.x) + (1.f - s0) * bf2f(sp.x)),
        f2bf(s1 * bf2f(ad.y) + (1.f - s1) * bf2f(sp.y)),
        f2bf(s2 * bf2f(ad.z) + (1.f - s2) * bf2f(sp.z)),
        f2bf(s3 * bf2f(ad.w) + (1.f - s3) * bf2f(sp.w)));
    *(ushort4*)(S + j) = o;
}

// G1 reduce: xg1b[b,n,c] (gconv A layout) + xg1T[(b,c)][n] (G2 Bt operand)
__global__ __launch_bounds__(256)
void reduceT(const u16* __restrict__ p, u16* __restrict__ xg1b,
             u16* __restrict__ xg1T) {
    __shared__ u16 t[64][68];
    int bx = blockIdx.x * 64, by = blockIdx.y * 64;   // bx: (b,c) cols, by: n rows
    int cg = threadIdx.x & 15, rg = threadIdx.x >> 4;
    int b = bx >> 6;
#pragma unroll
    for (int rr = 0; rr < 4; ++rr) {
        int row = rg * 4 + rr;
        size_t idx = (size_t)(by + row) * 2048 + bx + cg * 4;
        ushort4 q0 = *(const ushort4*)(p + idx);
        ushort4 q1 = *(const ushort4*)(p + PSTRIDE + idx);
        ushort4 q2 = *(const ushort4*)(p + 2 * PSTRIDE + idx);
        ushort4 q3 = *(const ushort4*)(p + 3 * PSTRIDE + idx);
        ushort4 v = make_ushort4(
            f2bf(bf2f(q0.x) + bf2f(q1.x) + bf2f(q2.x) + bf2f(q3.x)),
            f2bf(bf2f(q0.y) + bf2f(q1.y) + bf2f(q2.y) + bf2f(q3.y)),
            f2bf(bf2f(q0.z) + bf2f(q1.z) + bf2f(q2.z) + bf2f(q3.z)),
            f2bf(bf2f(q0.w) + bf2f(q1.w) + bf2f(q2.w) + bf2f(q3.w)));
        *(ushort4*)(xg1b + ((size_t)b * 2048 + by + row) * 64 + cg * 4) = v;
        *(ushort4*)(&t[row][cg * 4]) = v;
    }
    __syncthreads();
    int c = threadIdx.x & 63, g = threadIdx.x >> 6;
#pragma unroll
    for (int r = 0; r < 16; ++r) {
        int row = g * 16 + r;
        xg1T[(size_t)(bx + row) * 2048 + by + c] = t[c][row];
    }
}

// ---------------------------------------------------------------- gconv MFMA, barrier-free
// out[row=(b,n), o] = bias[n,o] + sum_d E[n,d] * (XG[row,:] @ Wp'_d)   K=192
// XG cols: [x (fp32, cast in reg) | xg1b | sum of 4 G2 partials]. All operands loaded
// straight into registers; only El (8 KB) lives in LDS; ONE barrier total.
__global__ __launch_bounds__(256, 2)
void gconv_mfma(const float* __restrict__ x, const u16* __restrict__ xg1,
                const u16* __restrict__ p, const u16* __restrict__ Wpb,
                const float* __restrict__ bias, const float* __restrict__ E,
                float* __restrict__ out) {
    __shared__ alignas(16) float El[16 * 128];  // 8 KB, [d][row]
    const int tid = threadIdx.x, lane = tid & 63, wave = tid >> 6;
    const int m0 = blockIdx.x * 128, nb = m0 & 2047, bB = m0 >> 11;
    const int wm = (wave >> 1) * 64, wn = (wave & 1) * 32;
    const int ml = lane & 15, c0l = lane >> 4;
    const int col_l = lane & 15, rl = (lane >> 4) * 4;

    // stage El transposed [d][128]
#pragma unroll
    for (int it = 0; it < 8; ++it) {
        int idx = tid + it * 256;
        El[idx] = E[(size_t)(nb + (idx & 127)) * 16 + (idx >> 7)];
    }
    __syncthreads();                      // the only barrier

    // A fragments direct from global (d-invariant). Chunk c = c0l + ks*4:
    // ks 0-1 -> x (fp32, c in [0,8)); ks 2-3 -> xg1 (c-8 in [0,8)); ks 4-5 -> 4-sum of
    // G2 partials (c-16 in [0,8)). Branches are wave-uniform per ks; loads coalesce to
    // 16 rows x 64-128B contiguous per wave.
    bf16x8 af[4][6];
#pragma unroll
    for (int i = 0; i < 4; ++i) {
        const int row = m0 + wm + i * 16 + ml;
        const int n = row & 2047;
#pragma unroll
        for (int ks = 0; ks < 2; ++ks) {
            const float* xp = x + (size_t)row * 64 + (c0l + ks * 4) * 8;
            float4 a = *(const float4*)xp, b4 = *(const float4*)(xp + 4);
            u16x8 v;
            v[0] = f2bf(a.x);  v[1] = f2bf(a.y);  v[2] = f2bf(a.z);  v[3] = f2bf(a.w);
            v[4] = f2bf(b4.x); v[5] = f2bf(b4.y); v[6] = f2bf(b4.z); v[7] = f2bf(b4.w);
            af[i][ks] = __builtin_bit_cast(bf16x8, v);
        }
#pragma unroll
        for (int ks = 2; ks < 4; ++ks)
            af[i][ks] = *(const bf16x8*)(xg1 + (size_t)row * 64 + (c0l + ks * 4 - 8) * 8);
#pragma unroll
        for (int ks = 4; ks < 6; ++ks) {
            const u16* pp = p + (size_t)n * 2048 + bB * 64 + (c0l + ks * 4 - 16) * 8;
            u16x8 q0 = *(const u16x8*)pp;
            u16x8 q1 = *(const u16x8*)(pp + PSTRIDE);
            u16x8 q2 = *(const u16x8*)(pp + 2 * PSTRIDE);
            u16x8 q3 = *(const u16x8*)(pp + 3 * PSTRIDE);
            u16x8 v;
#pragma unroll
            for (int tt = 0; tt < 8; ++tt)
                v[tt] = f2bf(bf2f(q0[tt]) + bf2f(q1[tt]) + bf2f(q2[tt]) + bf2f(q3[tt]));
            af[i][ks] = __builtin_bit_cast(bf16x8, v);
        }
    }

    // init out-acc from bias
    f32x4 oacc[4][2];
#pragma unroll
    for (int i = 0; i < 4; ++i)
#pragma unroll
        for (int j = 0; j < 2; ++j)
#pragma unroll
            for (int r = 0; r < 4; ++r)
                oacc[i][j][r] = bias[(size_t)(nb + wm + i * 16 + rl + r) * 64 + wn + j * 16 + col_l];

    // d-loop: B-frags straight from L2-resident Wpb; no barriers -> compiler pipelines
#pragma unroll 2
    for (int d = 0; d < 16; ++d) {
        bf16x8 bv[2][6];
#pragma unroll
        for (int j = 0; j < 2; ++j) {
            const u16* wp = Wpb + (size_t)(d * 64 + wn + j * 16 + ml) * 192 + c0l * 8;
#pragma unroll
            for (int ks = 0; ks < 6; ++ks)
                bv[j][ks] = *(const bf16x8*)(wp + ks * 32);
        }
        f32x4 tmp[4][2] = {};
#pragma unroll
        for (int ks = 0; ks < 6; ++ks)
#pragma unroll
            for (int i = 0; i < 4; ++i)
#pragma unroll
                for (int j = 0; j < 2; ++j)
                    tmp[i][j] = __builtin_amdgcn_mfma_f32_16x16x32_bf16(af[i][ks], bv[j][ks], tmp[i][j], 0, 0, 0);
        // scale-add: oacc += E[row,d] * tmp  (El broadcast, conflict-free b128)
#pragma unroll
        for (int i = 0; i < 4; ++i) {
            f32x4 ev = *(const f32x4*)(El + d * 128 + wm + i * 16 + rl);
#pragma unroll
            for (int r = 0; r < 4; ++r)
#pragma unroll
                for (int j = 0; j < 2; ++j)
                    oacc[i][j][r] = fmaf(ev[r], tmp[i][j][r], oacc[i][j][r]);
        }
    }
#pragma unroll
    for (int i = 0; i < 4; ++i)
#pragma unroll
        for (int j = 0; j < 2; ++j)
#pragma unroll
            for (int r = 0; r < 4; ++r)
                out[(size_t)(m0 + wm + i * 16 + rl + r) * 64 + wn + j * 16 + col_l] = oacc[i][j][r];
}

// ---------------------------------------------------------------- launch
extern "C" void kernel_launch(void* const* d_in, const int* in_sizes, int n_in,
                              void* d_out, int out_size, void* d_ws, size_t ws_size,
                              hipStream_t stream) {
    const float* x   = (const float*)d_in[0];   // [32,2048,64]
    const float* E   = (const float*)d_in[1];   // [2048,16]
    const float* adj = (const float*)d_in[2];   // [2048,2048]
    const float* Wp  = (const float*)d_in[3];   // [16,3,64,64]
    const float* bp  = (const float*)d_in[4];   // [16,64]
    const float* saw = (const float*)d_in[5];   // [2048,4096]
    float* out = (float*)d_out;

    char* ws = (char*)d_ws;
    const size_t MB = 1u << 20;
    u16*   Acat  = (u16*)(ws);                  // [0,16M)
    u16*   sawb  = (u16*)(ws + 16 * MB);        // [16,32M)
    u16*   XtT   = (u16*)(ws + 32 * MB);        // [32,40M)
    u16*   Wpb   = (u16*)(ws + 40 * MB);        // [40,40.4M)
    float* bias  = (float*)(ws + 41 * MB);      // [41,41.5M)
    float* zf    = (float*)(ws + 48 * MB);      // [48,64M) fp32 z (pre-softmax)
    u16*   part  = (u16*)(ws + 48 * MB);        // [48,80M) 4 x 8MB bf16 partials (after)
    u16*   S_bf  = (u16*)(ws + 16 * MB);        // [16,24M) after sawb dead
    u16*   xg1T  = (u16*)(ws + 24 * MB);        // [24,32M) after sawb dead
    u16*   xg1b  = (u16*)(ws);                  // [0,8M)   after Acat dead (post reduce_z)

    preamble<<<13648, 256, 0, stream>>>(E, adj, saw, x, Wp, bp, zf, Acat, sawb, XtT, Wpb, bias);
    softmax_rows<<<2048, 256, 0, stream>>>(zf, Acat);

    // z = Acat @ sawb^T, split-K=4
    gemm_bt<<<dim3(16, 16, 4), 256, 0, stream>>>(Acat, sawb, part, 2048, 2048, 4096, 1024);
    reduce_z<<<4096, 256, 0, stream>>>(part, Acat, S_bf);
    // G1: xg1 = S @ X, split-K=4
    gemm_bt<<<dim3(16, 16, 4), 256, 0, stream>>>(S_bf, XtT, part, 2048, 2048, 2048, 512);
    reduceT<<<dim3(32, 32), 256, 0, stream>>>(part, xg1b, xg1T);
    // G2: xg2raw = S @ xg1, split-K=4 (partials consumed directly by gconv)
    gemm_bt<<<dim3(16, 16, 4), 256, 0, stream>>>(S_bf, xg1T, part, 2048, 2048, 2048, 512);

    gconv_mfma<<<512, 256, 0, stream>>>(x, xg1b, part, Wpb, bias, E, out);
}

// Round 12
// 299.642 us; speedup vs baseline: 1.0150x; 1.0150x over previous
//
#include <hip/hip_runtime.h>

// AVWGCN: B=32, N=2048, C=64, O=64, K=3, D=16
// R12 changes vs R11 (gconv_mfma stuck at 65us regardless of barriers/LDS: the d-loop
// does 25.8 GF -- 16x algebraically redundant. Contract d FIRST):
//  - wgen: Wnb[n][o][ki] bf16 = sum_d E[n,d]*Wp'[d]  (0.8 GF, 50 MB -> L3-resident).
//    Runs as extra blocks of the softmax dispatch, reading fp32 Wpbf (chunks in regs).
//  - gconv_wn: one block per node n. A = [32 b-rows x 192] from n-major buffers
//    (xn[n][b][c] written by preamble transpose; xg1n by reduceT; G2 partials already
//    [n][(b,c)]); B = Wnb[n] (24 KB, gl_lds16 + XOR swizzle); 48 MFMAs; bias in init.
//    1.6 GF + ~50 KB/block streaming vs 25.8 GF before.
//  - Requires ~139 MB ws (xn 8 + Wnb 50.3 above the 80 MB map). kernel_launch branches
//    on ws_size (constant -> graph-safe); falls back to exact R11 path if short.
// Base workspace map (both modes, 80 MiB):
//  [0,16M) Acat -> xg1n/xg1b [0,8M)   [16,32M) sawb -> S_bf [16,24M) + xg1T [24,32M)
//  [32,40M) XtT  [40,40.4M) Wpb bf16  [41,41.5M) bias  [42,42.8M) Wpbf fp32
//  [48,80M) zf [48,64M) -> 4x bf16 split-K partials
// Wn mode extras: xn [80,88M), Wnb [88,138.4M)

typedef unsigned short u16;
typedef float f32x4 __attribute__((ext_vector_type(4)));
typedef __bf16 bf16x8 __attribute__((ext_vector_type(8)));
typedef unsigned short u16x8 __attribute__((ext_vector_type(8)));

#define PSTRIDE ((size_t)2048 * 2048)

__device__ __forceinline__ u16 f2bf(float f) {
    unsigned u = __float_as_uint(f);
    u += 0x7FFFu + ((u >> 16) & 1u);   // RNE
    return (u16)(u >> 16);
}
__device__ __forceinline__ float bf2f(u16 h) {
    return __uint_as_float((unsigned)h << 16);
}
__device__ __forceinline__ void gl_lds16(const void* g, void* l) {
    __builtin_amdgcn_global_load_lds(
        (const __attribute__((address_space(1))) unsigned*)g,
        (__attribute__((address_space(3))) unsigned*)l, 16, 0, 0);
}

// ---------------------------------------------------------------- preamble (fused)
// blocks [0,256): ee tile z=relu(E@E^T) fp32 | [256,4352): adj cast | [4352,12544):
// saw cast | [12544,13568): x -> XtT (+ xn if mode) | [13568,13648): prep Wpb/Wpbf/bias
__global__ __launch_bounds__(256)
void preamble(const float* __restrict__ E, const float* __restrict__ adj,
              const float* __restrict__ saw, const float* __restrict__ x,
              const float* __restrict__ Wp, const float* __restrict__ bp,
              float* __restrict__ zf, u16* __restrict__ Acat,
              u16* __restrict__ sawb, u16* __restrict__ xtT,
              u16* __restrict__ Wpb, float* __restrict__ Wpbf,
              float* __restrict__ bias, u16* __restrict__ xn, int mode) {
    __shared__ u16 t[64][65];
    __shared__ float Bp[1024];
    const int bid = blockIdx.x, tid = threadIdx.x;

    if (bid < 256) {
        const int c0 = (bid & 31) * 64, r0 = (bid >> 5) * 256;
        const int r = r0 + tid;
        const float4* Er = (const float4*)(E + (size_t)r * 16);
        float4 e0 = Er[0], e1 = Er[1], e2 = Er[2], e3 = Er[3];
        *(float4*)(Bp + tid * 4) = *(const float4*)(E + (size_t)c0 * 16 + tid * 4);
        __syncthreads();
        float* zr = zf + (size_t)r * 2048 + c0;
#pragma unroll
        for (int cc = 0; cc < 4; ++cc) {
            float acc[16];
#pragma unroll
            for (int c = 0; c < 16; ++c) {
                const float* bp2 = Bp + (cc * 16 + c) * 16;
                float s = 0.f;
                s = fmaf(e0.x, bp2[0], s);  s = fmaf(e0.y, bp2[1], s);
                s = fmaf(e0.z, bp2[2], s);  s = fmaf(e0.w, bp2[3], s);
                s = fmaf(e1.x, bp2[4], s);  s = fmaf(e1.y, bp2[5], s);
                s = fmaf(e1.z, bp2[6], s);  s = fmaf(e1.w, bp2[7], s);
                s = fmaf(e2.x, bp2[8], s);  s = fmaf(e2.y, bp2[9], s);
                s = fmaf(e2.z, bp2[10], s); s = fmaf(e2.w, bp2[11], s);
                s = fmaf(e3.x, bp2[12], s); s = fmaf(e3.y, bp2[13], s);
                s = fmaf(e3.z, bp2[14], s); s = fmaf(e3.w, bp2[15], s);
                acc[c] = fmaxf(s, 0.f);
            }
#pragma unroll
            for (int q = 0; q < 4; ++q)
                *(float4*)(zr + cc * 16 + q * 4) =
                    make_float4(acc[q * 4], acc[q * 4 + 1], acc[q * 4 + 2], acc[q * 4 + 3]);
        }
    } else if (bid < 4352) {
        size_t j = ((size_t)(bid - 256) * 256 + tid) * 4;
        float4 v = *(const float4*)(adj + j);
        int n = (int)(j >> 11), c = (int)(j & 2047);
        ushort4 o = make_ushort4(f2bf(v.x), f2bf(v.y), f2bf(v.z), f2bf(v.w));
        *(ushort4*)(Acat + (size_t)n * 4096 + 2048 + c) = o;
    } else if (bid < 12544) {
        size_t j = ((size_t)(bid - 4352) * 256 + tid) * 4;
        float4 v = *(const float4*)(saw + j);
        ushort4 o = make_ushort4(f2bf(v.x), f2bf(v.y), f2bf(v.z), f2bf(v.w));
        *(ushort4*)(sawb + j) = o;
    } else if (bid < 13568) {
        int local = bid - 12544;
        int m0 = (local & 31) * 64, b = local >> 5;
        int c = tid & 63, g = tid >> 6;
#pragma unroll
        for (int r = 0; r < 16; ++r) {
            int mm = g * 16 + r;
            t[mm][c] = f2bf(x[((size_t)b * 2048 + m0 + mm) * 64 + c]);
        }
        __syncthreads();
#pragma unroll
        for (int r = 0; r < 16; ++r) {
            int cc = g * 16 + r;
            xtT[((size_t)b * 64 + cc) * 2048 + m0 + c] = t[c][cc];
        }
        if (mode) {   // xn[n][(b,c)] for gconv_wn A-tiles (128B rows, coalesced)
#pragma unroll
            for (int r = 0; r < 16; ++r) {
                int mm = g * 16 + r;
                xn[((size_t)(m0 + mm)) * 2048 + b * 64 + c] = t[mm][c];
            }
        }
    } else {
        int local = bid - 13568;
        if (local < 16) {
            const int d = local;
            const float* base = Wp + (size_t)d * 12288;    // [k][i][o]
            for (int idx = tid; idx < 12288; idx += 256) {
                int o = idx / 192, ki = idx - o * 192;
                int k = ki >> 6, i = ki & 63;
                float v;
                if (k == 0)      v = base[i * 64 + o] - base[2 * 4096 + i * 64 + o];
                else if (k == 1) v = base[4096 + i * 64 + o];
                else             v = 2.f * base[2 * 4096 + i * 64 + o];
                size_t dst = (size_t)(d * 64 + o) * 192 + ki;
                Wpb[dst] = f2bf(v);
                Wpbf[dst] = v;
            }
        } else {
            const int nb = local - 16;
#pragma unroll
            for (int it = 0; it < 8; ++it) {
                int idx = tid + it * 256;
                int n = nb * 32 + (idx >> 6), o = idx & 63;
                float s = 0.f;
#pragma unroll
                for (int d = 0; d < 16; ++d) s = fmaf(E[n * 16 + d], bp[d * 64 + o], s);
                bias[(size_t)n * 64 + o] = s;
            }
        }
    }
}

// ---------------------------------------------------------------- mid: softmax + wgen
// blocks [0,2048): row softmax zf -> Acat left. blocks [2048,2432) (Wn mode only):
// Wnb[n][o][ki] = sum_d E[n,d]*Wpbf[d][o][ki]  (12 ki-chunks x 32 n-groups).
__global__ __launch_bounds__(256)
void mid(const float* __restrict__ zf, u16* __restrict__ Acat,
         const float* __restrict__ E, const float* __restrict__ Wpbf,
         u16* __restrict__ Wnb) {
    __shared__ float red[4];
    __shared__ float Es[64 * 16];
    const int bid = blockIdx.x, tid = threadIdx.x;
    if (bid < 2048) {
        const int n = bid, lane = tid & 63, wave = tid >> 6;
        const float* zr = zf + (size_t)n * 2048;
        float4 a = *(const float4*)(zr + tid * 8);
        float4 b = *(const float4*)(zr + tid * 8 + 4);
        float mx = fmaxf(fmaxf(fmaxf(a.x, a.y), fmaxf(a.z, a.w)),
                         fmaxf(fmaxf(b.x, b.y), fmaxf(b.z, b.w)));
        for (int off = 32; off; off >>= 1) mx = fmaxf(mx, __shfl_down(mx, off, 64));
        if (lane == 0) red[wave] = mx;
        __syncthreads();
        mx = fmaxf(fmaxf(red[0], red[1]), fmaxf(red[2], red[3]));
        __syncthreads();
        float v[8] = {__expf(a.x - mx), __expf(a.y - mx), __expf(a.z - mx), __expf(a.w - mx),
                      __expf(b.x - mx), __expf(b.y - mx), __expf(b.z - mx), __expf(b.w - mx)};
        float sum = v[0] + v[1] + v[2] + v[3] + v[4] + v[5] + v[6] + v[7];
        for (int off = 32; off; off >>= 1) sum += __shfl_down(sum, off, 64);
        if (lane == 0) red[wave] = sum;
        __syncthreads();
        sum = red[0] + red[1] + red[2] + red[3];
        float inv = 1.f / sum;
        u16* orow = Acat + (size_t)n * 4096 + tid * 8;
        *(ushort4*)orow = make_ushort4(f2bf(v[0] * inv), f2bf(v[1] * inv),
                                       f2bf(v[2] * inv), f2bf(v[3] * inv));
        *(ushort4*)(orow + 4) = make_ushort4(f2bf(v[4] * inv), f2bf(v[5] * inv),
                                             f2bf(v[6] * inv), f2bf(v[7] * inv));
    } else {
        const int w = bid - 2048;
        const int c0 = (w % 12) * 1024, n0 = (w / 12) * 64;
        for (int j = tid; j < 1024; j += 256) Es[j] = E[(size_t)n0 * 16 + j];
        float4 wf[16];
#pragma unroll
        for (int d = 0; d < 16; ++d)
            wf[d] = *(const float4*)(Wpbf + (size_t)d * 12288 + c0 + tid * 4);
        __syncthreads();
        for (int nl = 0; nl < 64; ++nl) {
            float4 s = make_float4(0.f, 0.f, 0.f, 0.f);
#pragma unroll
            for (int d = 0; d < 16; ++d) {
                float e = Es[nl * 16 + d];
                s.x = fmaf(e, wf[d].x, s.x);
                s.y = fmaf(e, wf[d].y, s.y);
                s.z = fmaf(e, wf[d].z, s.z);
                s.w = fmaf(e, wf[d].w, s.w);
            }
            *(ushort4*)(Wnb + (size_t)(n0 + nl) * 12288 + c0 + tid * 4) =
                make_ushort4(f2bf(s.x), f2bf(s.y), f2bf(s.z), f2bf(s.w));
        }
    }
}

// ---------------------------------------------------------------- GEMM 128x128, BK=64, split-K
__global__ __launch_bounds__(256, 3)
void gemm_bt(const u16* __restrict__ A, const u16* __restrict__ Bt,
             u16* __restrict__ Cp, int M, int N, int K, int Kh) {
    __shared__ alignas(16) u16 As[128 * 64];
    __shared__ alignas(16) u16 Bs[128 * 64];
    const int tid = threadIdx.x, lane = tid & 63, wave = tid >> 6;
    const int m0 = blockIdx.y * 128, n0 = blockIdx.x * 128;
    const int wm = (wave >> 1) * 64, wn = (wave & 1) * 64;
    const int kbeg = blockIdx.z * Kh, kend = kbeg + Kh;
    const int ml = lane & 15, c0l = lane >> 4;
    f32x4 acc[4][4] = {};

    int baseA[4], mskA[4], baseB[4], mskB[4];
#pragma unroll
    for (int i = 0; i < 4; ++i) { int m = wm + i * 16 + ml; baseA[i] = m * 8; mskA[i] = m & 7; }
#pragma unroll
    for (int j = 0; j < 4; ++j) { int nn = wn + j * 16 + ml; baseB[j] = nn * 8; mskB[j] = nn & 7; }

    for (int k0 = kbeg; k0 < kend; k0 += 64) {
#pragma unroll
        for (int r = 0; r < 4; ++r) {
            int s = wave * 64 + r * 256 + lane;
            int row = s >> 3, gc = (s & 7) ^ (row & 7);
            gl_lds16(A + (size_t)(m0 + row) * K + k0 + gc * 8, As + (size_t)s * 8);
        }
#pragma unroll
        for (int r = 0; r < 4; ++r) {
            int s = wave * 64 + r * 256 + lane;
            int row = s >> 3, gc = (s & 7) ^ (row & 7);
            gl_lds16(Bt + (size_t)(n0 + row) * K + k0 + gc * 8, Bs + (size_t)s * 8);
        }
        __syncthreads();
#pragma unroll
        for (int ks4 = 0; ks4 < 8; ks4 += 4) {
            bf16x8 af[4], bv[4];
#pragma unroll
            for (int i = 0; i < 4; ++i)
                af[i] = *(const bf16x8*)(As + (baseA[i] + ((c0l + ks4) ^ mskA[i])) * 8);
#pragma unroll
            for (int j = 0; j < 4; ++j)
                bv[j] = *(const bf16x8*)(Bs + (baseB[j] + ((c0l + ks4) ^ mskB[j])) * 8);
#pragma unroll
            for (int i = 0; i < 4; ++i)
#pragma unroll
                for (int j = 0; j < 4; ++j)
                    acc[i][j] = __builtin_amdgcn_mfma_f32_16x16x32_bf16(af[i], bv[j], acc[i][j], 0, 0, 0);
        }
        __syncthreads();
    }

    const int col_l = lane & 15, row_l = (lane >> 4) * 4;
    u16* Cz = Cp + (size_t)blockIdx.z * M * N;
#pragma unroll
    for (int i = 0; i < 4; ++i)
#pragma unroll
        for (int j = 0; j < 4; ++j)
#pragma unroll
            for (int r = 0; r < 4; ++r) {
                int row = m0 + wm + i * 16 + row_l + r;
                int col = n0 + wn + j * 16 + col_l;
                Cz[(size_t)row * N + col] = f2bf(acc[i][j][r]);
            }
}

// ---------------------------------------------------------------- reduce_z
__global__ __launch_bounds__(256)
void reduce_z(const u16* __restrict__ p, const u16* __restrict__ Acat,
              u16* __restrict__ S) {
    size_t j = ((size_t)blockIdx.x * 256 + threadIdx.x) * 4;
    ushort4 p0 = *(const ushort4*)(p + j);
    ushort4 p1 = *(const ushort4*)(p + PSTRIDE + j);
    ushort4 p2 = *(const ushort4*)(p + 2 * PSTRIDE + j);
    ushort4 p3 = *(const ushort4*)(p + 3 * PSTRIDE + j);
    int row = (int)(j >> 11), col = (int)(j & 2047);
    ushort4 sp = *(const ushort4*)(Acat + (size_t)row * 4096 + col);
    ushort4 ad = *(const ushort4*)(Acat + (size_t)row * 4096 + 2048 + col);
    float z0 = bf2f(p0.x) + bf2f(p1.x) + bf2f(p2.x) + bf2f(p3.x);
    float z1 = bf2f(p0.y) + bf2f(p1.y) + bf2f(p2.y) + bf2f(p3.y);
    float z2 = bf2f(p0.z) + bf2f(p1.z) + bf2f(p2.z) + bf2f(p3.z);
    float z3 = bf2f(p0.w) + bf2f(p1.w) + bf2f(p2.w) + bf2f(p3.w);
    float s0 = 1.f / (1.f + __expf(-z0)), s1 = 1.f / (1.f + __expf(-z1));
    float s2 = 1.f / (1.f + __expf(-z2)), s3 = 1.f / (1.f + __expf(-z3));
    ushort4 o = make_ushort4(
        f2bf(s0 * bf2f(ad.x) + (1.f - s0) * bf2f(sp.x)),
        f2bf(s1 * bf2f(ad.y) + (1.f - s1) * bf2f(sp.y)),
        f2bf(s2 * bf2f(ad.z) + (1.f - s2) * bf2f(sp.z)),
        f2bf(s3 * bf2f(ad.w) + (1.f - s3) * bf2f(sp.w)));
    *(ushort4*)(S + j) = o;
}

// ---------------------------------------------------------------- reduceT
// mode 1: xg1o = xg1n[n][(b,c)].  mode 0: xg1o = xg1b[b][n][c] (legacy).  +xg1T always.
__global__ __launch_bounds__(256)
void reduceT(const u16* __restrict__ p, u16* __restrict__ xg1o,
             u16* __restrict__ xg1T, int mode) {
    __shared__ u16 t[64][68];
    int bx = blockIdx.x * 64, by = blockIdx.y * 64;
    int cg = threadIdx.x & 15, rg = threadIdx.x >> 4;
    int b = bx >> 6;
#pragma unroll
    for (int rr = 0; rr < 4; ++rr) {
        int row = rg * 4 + rr;
        size_t idx = (size_t)(by + row) * 2048 + bx + cg * 4;
        ushort4 q0 = *(const ushort4*)(p + idx);
        ushort4 q1 = *(const ushort4*)(p + PSTRIDE + idx);
        ushort4 q2 = *(const ushort4*)(p + 2 * PSTRIDE + idx);
        ushort4 q3 = *(const ushort4*)(p + 3 * PSTRIDE + idx);
        ushort4 v = make_ushort4(
            f2bf(bf2f(q0.x) + bf2f(q1.x) + bf2f(q2.x) + bf2f(q3.x)),
            f2bf(bf2f(q0.y) + bf2f(q1.y) + bf2f(q2.y) + bf2f(q3.y)),
            f2bf(bf2f(q0.z) + bf2f(q1.z) + bf2f(q2.z) + bf2f(q3.z)),
            f2bf(bf2f(q0.w) + bf2f(q1.w) + bf2f(q2.w) + bf2f(q3.w)));
        if (mode) *(ushort4*)(xg1o + idx) = v;                                    // [n][(b,c)]
        else      *(ushort4*)(xg1o + ((size_t)b * 2048 + by + row) * 64 + cg * 4) = v;
        *(ushort4*)(&t[row][cg * 4]) = v;
    }
    __syncthreads();
    int c = threadIdx.x & 63, g = threadIdx.x >> 6;
#pragma unroll
    for (int r = 0; r < 16; ++r) {
        int row = g * 16 + r;
        xg1T[(size_t)(bx + row) * 2048 + by + c] = t[c][row];
    }
}

// ---------------------------------------------------------------- gconv_wn (Wn mode)
// block = node n. out[(b,n),o] = bias[n,o] + XG_n[b,:] @ Wnb[n]^T   (K=192, M=32, N=64)
__global__ __launch_bounds__(256, 4)
void gconv_wn(const u16* __restrict__ xn, const u16* __restrict__ xg1n,
              const u16* __restrict__ p, const u16* __restrict__ Wnb,
              const float* __restrict__ bias, float* __restrict__ out) {
    __shared__ alignas(16) u16 As[32 * 192];   // 12 KB, XOR-swizzled chunks
    __shared__ alignas(16) u16 Bs[64 * 192];   // 24 KB
    const int n = blockIdx.x, tid = threadIdx.x;
    const int lane = tid & 63, wave = tid >> 6;
    const int wn2 = wave * 16;
    const int ml = lane & 15, c0l = lane >> 4;
    const int col = lane & 15, rl = (lane >> 4) * 4;

    // B: Wnb[n] 1536 chunks via gl_lds16 (full-wave lane-linear)
#pragma unroll
    for (int it = 0; it < 6; ++it) {
        int s = tid + it * 256;
        int row = s / 24, sc = s - row * 24;
        int gc = (sc & 24) | ((sc ^ row) & 7);
        gl_lds16(Wnb + (size_t)n * 12288 + (size_t)row * 192 + gc * 8, Bs + (size_t)s * 8);
    }
    // A: 768 chunks via plain loads + ds_write (divergent sources -> no gl_lds16)
#pragma unroll
    for (int it = 0; it < 3; ++it) {
        int s = tid + it * 256;
        int row = s / 24, sc = s - row * 24;      // row = b
        int gc = (sc & 24) | ((sc ^ row) & 7);
        u16x8 v;
        if (gc < 8) {
            v = *(const u16x8*)(xn + (size_t)n * 2048 + row * 64 + (gc & 7) * 8);
        } else if (gc < 16) {
            v = *(const u16x8*)(xg1n + (size_t)n * 2048 + row * 64 + (gc & 7) * 8);
        } else {
            const u16* pp = p + (size_t)n * 2048 + row * 64 + (gc & 7) * 8;
            u16x8 q0 = *(const u16x8*)pp;
            u16x8 q1 = *(const u16x8*)(pp + PSTRIDE);
            u16x8 q2 = *(const u16x8*)(pp + 2 * PSTRIDE);
            u16x8 q3 = *(const u16x8*)(pp + 3 * PSTRIDE);
#pragma unroll
            for (int tt = 0; tt < 8; ++tt)
                v[tt] = f2bf(bf2f(q0[tt]) + bf2f(q1[tt]) + bf2f(q2[tt]) + bf2f(q3[tt]));
        }
        *(u16x8*)(As + (size_t)s * 8) = v;
    }
    // acc init from bias (same for all rows)
    float bv0 = bias[(size_t)n * 64 + wn2 + col];
    f32x4 acc[2];
#pragma unroll
    for (int mt = 0; mt < 2; ++mt)
#pragma unroll
        for (int r = 0; r < 4; ++r) acc[mt][r] = bv0;
    __syncthreads();

#pragma unroll
    for (int ks = 0; ks < 6; ++ks) {
        int c = c0l + ks * 4;
        int o = wn2 + ml;
        bf16x8 bfrag = *(const bf16x8*)(Bs + (o * 24 + ((c & 24) | ((c ^ (o & 7)) & 7))) * 8);
#pragma unroll
        for (int mt = 0; mt < 2; ++mt) {
            int m = mt * 16 + ml;
            bf16x8 afrag = *(const bf16x8*)(As + (m * 24 + ((c & 24) | ((c ^ (m & 7)) & 7))) * 8);
            acc[mt] = __builtin_amdgcn_mfma_f32_16x16x32_bf16(afrag, bfrag, acc[mt], 0, 0, 0);
        }
    }
#pragma unroll
    for (int mt = 0; mt < 2; ++mt)
#pragma unroll
        for (int r = 0; r < 4; ++r) {
            int b = mt * 16 + rl + r;
            out[((size_t)b * 2048 + n) * 64 + wn2 + col] = acc[mt][r];
        }
}

// ---------------------------------------------------------------- gconv_mfma (legacy fallback, R11)
__global__ __launch_bounds__(256, 2)
void gconv_mfma(const float* __restrict__ x, const u16* __restrict__ xg1,
                const u16* __restrict__ p, const u16* __restrict__ Wpb,
                const float* __restrict__ bias, const float* __restrict__ E,
                float* __restrict__ out) {
    __shared__ alignas(16) float El[16 * 128];
    const int tid = threadIdx.x, lane = tid & 63, wave = tid >> 6;
    const int m0 = blockIdx.x * 128, nb = m0 & 2047, bB = m0 >> 11;
    const int wm = (wave >> 1) * 64, wn = (wave & 1) * 32;
    const int ml = lane & 15, c0l = lane >> 4;
    const int col_l = lane & 15, rl = (lane >> 4) * 4;

#pragma unroll
    for (int it = 0; it < 8; ++it) {
        int idx = tid + it * 256;
        El[idx] = E[(size_t)(nb + (idx & 127)) * 16 + (idx >> 7)];
    }
    __syncthreads();

    bf16x8 af[4][6];
#pragma unroll
    for (int i = 0; i < 4; ++i) {
        const int row = m0 + wm + i * 16 + ml;
        const int n = row & 2047;
#pragma unroll
        for (int ks = 0; ks < 2; ++ks) {
            const float* xp = x + (size_t)row * 64 + (c0l + ks * 4) * 8;
            float4 a = *(const float4*)xp, b4 = *(const float4*)(xp + 4);
            u16x8 v;
            v[0] = f2bf(a.x);  v[1] = f2bf(a.y);  v[2] = f2bf(a.z);  v[3] = f2bf(a.w);
            v[4] = f2bf(b4.x); v[5] = f2bf(b4.y); v[6] = f2bf(b4.z); v[7] = f2bf(b4.w);
            af[i][ks] = __builtin_bit_cast(bf16x8, v);
        }
#pragma unroll
        for (int ks = 2; ks < 4; ++ks)
            af[i][ks] = *(const bf16x8*)(xg1 + (size_t)row * 64 + (c0l + ks * 4 - 8) * 8);
#pragma unroll
        for (int ks = 4; ks < 6; ++ks) {
            const u16* pp = p + (size_t)n * 2048 + bB * 64 + (c0l + ks * 4 - 16) * 8;
            u16x8 q0 = *(const u16x8*)pp;
            u16x8 q1 = *(const u16x8*)(pp + PSTRIDE);
            u16x8 q2 = *(const u16x8*)(pp + 2 * PSTRIDE);
            u16x8 q3 = *(const u16x8*)(pp + 3 * PSTRIDE);
            u16x8 v;
#pragma unroll
            for (int tt = 0; tt < 8; ++tt)
                v[tt] = f2bf(bf2f(q0[tt]) + bf2f(q1[tt]) + bf2f(q2[tt]) + bf2f(q3[tt]));
            af[i][ks] = __builtin_bit_cast(bf16x8, v);
        }
    }

    f32x4 oacc[4][2];
#pragma unroll
    for (int i = 0; i < 4; ++i)
#pragma unroll
        for (int j = 0; j < 2; ++j)
#pragma unroll
            for (int r = 0; r < 4; ++r)
                oacc[i][j][r] = bias[(size_t)(nb + wm + i * 16 + rl + r) * 64 + wn + j * 16 + col_l];

#pragma unroll 2
    for (int d = 0; d < 16; ++d) {
        bf16x8 bv[2][6];
#pragma unroll
        for (int j = 0; j < 2; ++j) {
            const u16* wp = Wpb + (size_t)(d * 64 + wn + j * 16 + ml) * 192 + c0l * 8;
#pragma unroll
            for (int ks = 0; ks < 6; ++ks)
                bv[j][ks] = *(const bf16x8*)(wp + ks * 32);
        }
        f32x4 tmp[4][2] = {};
#pragma unroll
        for (int ks = 0; ks < 6; ++ks)
#pragma unroll
            for (int i = 0; i < 4; ++i)
#pragma unroll
                for (int j = 0; j < 2; ++j)
                    tmp[i][j] = __builtin_amdgcn_mfma_f32_16x16x32_bf16(af[i][ks], bv[j][ks], tmp[i][j], 0, 0, 0);
#pragma unroll
        for (int i = 0; i < 4; ++i) {
            f32x4 ev = *(const f32x4*)(El + d * 128 + wm + i * 16 + rl);
#pragma unroll
            for (int r = 0; r < 4; ++r)
#pragma unroll
                for (int j = 0; j < 2; ++j)
                    oacc[i][j][r] = fmaf(ev[r], tmp[i][j][r], oacc[i][j][r]);
        }
    }
#pragma unroll
    for (int i = 0; i < 4; ++i)
#pragma unroll
        for (int j = 0; j < 2; ++j)
#pragma unroll
            for (int r = 0; r < 4; ++r)
                out[(size_t)(m0 + wm + i * 16 + rl + r) * 64 + wn + j * 16 + col_l] = oacc[i][j][r];
}

// ---------------------------------------------------------------- launch
extern "C" void kernel_launch(void* const* d_in, const int* in_sizes, int n_in,
                              void* d_out, int out_size, void* d_ws, size_t ws_size,
                              hipStream_t stream) {
    const float* x   = (const float*)d_in[0];
    const float* E   = (const float*)d_in[1];
    const float* adj = (const float*)d_in[2];
    const float* Wp  = (const float*)d_in[3];
    const float* bp  = (const float*)d_in[4];
    const float* saw = (const float*)d_in[5];
    float* out = (float*)d_out;

    char* ws = (char*)d_ws;
    const size_t MB = 1u << 20;
    const int wn_mode = (ws_size >= 140 * MB) ? 1 : 0;

    u16*   Acat  = (u16*)(ws);                  // [0,16M)
    u16*   sawb  = (u16*)(ws + 16 * MB);        // [16,32M)
    u16*   XtT   = (u16*)(ws + 32 * MB);        // [32,40M)
    u16*   Wpb   = (u16*)(ws + 40 * MB);        // [40,40.4M) bf16
    float* bias  = (float*)(ws + 41 * MB);      // [41,41.5M)
    float* Wpbf  = (float*)(ws + 42 * MB);      // [42,42.8M) fp32
    float* zf    = (float*)(ws + 48 * MB);      // [48,64M)
    u16*   part  = (u16*)(ws + 48 * MB);        // [48,80M)
    u16*   S_bf  = (u16*)(ws + 16 * MB);        // [16,24M)
    u16*   xg1T  = (u16*)(ws + 24 * MB);        // [24,32M)
    u16*   xg1o  = (u16*)(ws);                  // [0,8M)  xg1n (wn) / xg1b (legacy)
    u16*   xn    = (u16*)(ws + 80 * MB);        // [80,88M)   wn only
    u16*   Wnb   = (u16*)(ws + 88 * MB);        // [88,138.4M) wn only

    preamble<<<13648, 256, 0, stream>>>(E, adj, saw, x, Wp, bp, zf, Acat, sawb, XtT,
                                        Wpb, Wpbf, bias, xn, wn_mode);
    mid<<<wn_mode ? 2432 : 2048, 256, 0, stream>>>(zf, Acat, E, Wpbf, Wnb);

    gemm_bt<<<dim3(16, 16, 4), 256, 0, stream>>>(Acat, sawb, part, 2048, 2048, 4096, 1024);
    reduce_z<<<4096, 256, 0, stream>>>(part, Acat, S_bf);
    gemm_bt<<<dim3(16, 16, 4), 256, 0, stream>>>(S_bf, XtT, part, 2048, 2048, 2048, 512);
    reduceT<<<dim3(32, 32), 256, 0, stream>>>(part, xg1o, xg1T, wn_mode);
    gemm_bt<<<dim3(16, 16, 4), 256, 0, stream>>>(S_bf, xg1T, part, 2048, 2048, 2048, 512);

    if (wn_mode)
        gconv_wn<<<2048, 256, 0, stream>>>(xn, xg1o, part, Wnb, bias, out);
    else
        gconv_mfma<<<512, 256, 0, stream>>>(x, xg1o, part, Wpb, bias, E, out);
}

// Round 13
// 278.016 us; speedup vs baseline: 1.0940x; 1.0778x over previous
//
#include <hip/hip_runtime.h>

// AVWGCN: B=32, N=2048, C=64, O=64, K=3, D=16
// R13 changes vs R12 (z-GEMM #1 at 54.6us, MfmaUtil 24%: glds + barrier vmcnt(0) drain
// exposes ~900cy staging latency per K-iter):
//  - gemm_bt: register-staged pipeline. Tile k+1 loaded global->VGPR (8x u16x8) BEFORE
//    tile k's 32 MFMAs; ds_write after compute; vmcnt wait overlaps MFMAs instead of
//    stalling pre-compute. Same XOR-swizzled LDS layout (lane-linear slots).
//  - wgen rebalanced: 768 blocks x 32 n (was 384 x 64) -> shorter mid-dispatch tail.
// Rest identical to R12 (Wn-mode gconv, fused preamble/mid, 8 dispatches).
// Workspace map unchanged; Wn mode needs >=140 MB (fallback path kept).

typedef unsigned short u16;
typedef float f32x4 __attribute__((ext_vector_type(4)));
typedef __bf16 bf16x8 __attribute__((ext_vector_type(8)));
typedef unsigned short u16x8 __attribute__((ext_vector_type(8)));

#define PSTRIDE ((size_t)2048 * 2048)

__device__ __forceinline__ u16 f2bf(float f) {
    unsigned u = __float_as_uint(f);
    u += 0x7FFFu + ((u >> 16) & 1u);   // RNE
    return (u16)(u >> 16);
}
__device__ __forceinline__ float bf2f(u16 h) {
    return __uint_as_float((unsigned)h << 16);
}
__device__ __forceinline__ void gl_lds16(const void* g, void* l) {
    __builtin_amdgcn_global_load_lds(
        (const __attribute__((address_space(1))) unsigned*)g,
        (__attribute__((address_space(3))) unsigned*)l, 16, 0, 0);
}

// ---------------------------------------------------------------- preamble (fused)
__global__ __launch_bounds__(256)
void preamble(const float* __restrict__ E, const float* __restrict__ adj,
              const float* __restrict__ saw, const float* __restrict__ x,
              const float* __restrict__ Wp, const float* __restrict__ bp,
              float* __restrict__ zf, u16* __restrict__ Acat,
              u16* __restrict__ sawb, u16* __restrict__ xtT,
              u16* __restrict__ Wpb, float* __restrict__ Wpbf,
              float* __restrict__ bias, u16* __restrict__ xn, int mode) {
    __shared__ u16 t[64][65];
    __shared__ float Bp[1024];
    const int bid = blockIdx.x, tid = threadIdx.x;

    if (bid < 256) {
        const int c0 = (bid & 31) * 64, r0 = (bid >> 5) * 256;
        const int r = r0 + tid;
        const float4* Er = (const float4*)(E + (size_t)r * 16);
        float4 e0 = Er[0], e1 = Er[1], e2 = Er[2], e3 = Er[3];
        *(float4*)(Bp + tid * 4) = *(const float4*)(E + (size_t)c0 * 16 + tid * 4);
        __syncthreads();
        float* zr = zf + (size_t)r * 2048 + c0;
#pragma unroll
        for (int cc = 0; cc < 4; ++cc) {
            float acc[16];
#pragma unroll
            for (int c = 0; c < 16; ++c) {
                const float* bp2 = Bp + (cc * 16 + c) * 16;
                float s = 0.f;
                s = fmaf(e0.x, bp2[0], s);  s = fmaf(e0.y, bp2[1], s);
                s = fmaf(e0.z, bp2[2], s);  s = fmaf(e0.w, bp2[3], s);
                s = fmaf(e1.x, bp2[4], s);  s = fmaf(e1.y, bp2[5], s);
                s = fmaf(e1.z, bp2[6], s);  s = fmaf(e1.w, bp2[7], s);
                s = fmaf(e2.x, bp2[8], s);  s = fmaf(e2.y, bp2[9], s);
                s = fmaf(e2.z, bp2[10], s); s = fmaf(e2.w, bp2[11], s);
                s = fmaf(e3.x, bp2[12], s); s = fmaf(e3.y, bp2[13], s);
                s = fmaf(e3.z, bp2[14], s); s = fmaf(e3.w, bp2[15], s);
                acc[c] = fmaxf(s, 0.f);
            }
#pragma unroll
            for (int q = 0; q < 4; ++q)
                *(float4*)(zr + cc * 16 + q * 4) =
                    make_float4(acc[q * 4], acc[q * 4 + 1], acc[q * 4 + 2], acc[q * 4 + 3]);
        }
    } else if (bid < 4352) {
        size_t j = ((size_t)(bid - 256) * 256 + tid) * 4;
        float4 v = *(const float4*)(adj + j);
        int n = (int)(j >> 11), c = (int)(j & 2047);
        ushort4 o = make_ushort4(f2bf(v.x), f2bf(v.y), f2bf(v.z), f2bf(v.w));
        *(ushort4*)(Acat + (size_t)n * 4096 + 2048 + c) = o;
    } else if (bid < 12544) {
        size_t j = ((size_t)(bid - 4352) * 256 + tid) * 4;
        float4 v = *(const float4*)(saw + j);
        ushort4 o = make_ushort4(f2bf(v.x), f2bf(v.y), f2bf(v.z), f2bf(v.w));
        *(ushort4*)(sawb + j) = o;
    } else if (bid < 13568) {
        int local = bid - 12544;
        int m0 = (local & 31) * 64, b = local >> 5;
        int c = tid & 63, g = tid >> 6;
#pragma unroll
        for (int r = 0; r < 16; ++r) {
            int mm = g * 16 + r;
            t[mm][c] = f2bf(x[((size_t)b * 2048 + m0 + mm) * 64 + c]);
        }
        __syncthreads();
#pragma unroll
        for (int r = 0; r < 16; ++r) {
            int cc = g * 16 + r;
            xtT[((size_t)b * 64 + cc) * 2048 + m0 + c] = t[c][cc];
        }
        if (mode) {
#pragma unroll
            for (int r = 0; r < 16; ++r) {
                int mm = g * 16 + r;
                xn[((size_t)(m0 + mm)) * 2048 + b * 64 + c] = t[mm][c];
            }
        }
    } else {
        int local = bid - 13568;
        if (local < 16) {
            const int d = local;
            const float* base = Wp + (size_t)d * 12288;    // [k][i][o]
            for (int idx = tid; idx < 12288; idx += 256) {
                int o = idx / 192, ki = idx - o * 192;
                int k = ki >> 6, i = ki & 63;
                float v;
                if (k == 0)      v = base[i * 64 + o] - base[2 * 4096 + i * 64 + o];
                else if (k == 1) v = base[4096 + i * 64 + o];
                else             v = 2.f * base[2 * 4096 + i * 64 + o];
                size_t dst = (size_t)(d * 64 + o) * 192 + ki;
                Wpb[dst] = f2bf(v);
                Wpbf[dst] = v;
            }
        } else {
            const int nb = local - 16;
#pragma unroll
            for (int it = 0; it < 8; ++it) {
                int idx = tid + it * 256;
                int n = nb * 32 + (idx >> 6), o = idx & 63;
                float s = 0.f;
#pragma unroll
                for (int d = 0; d < 16; ++d) s = fmaf(E[n * 16 + d], bp[d * 64 + o], s);
                bias[(size_t)n * 64 + o] = s;
            }
        }
    }
}

// ---------------------------------------------------------------- mid: softmax + wgen
// [0,2048): row softmax. [2048,2816) Wn mode: Wnb chunks, 12 ki x 64 n-groups of 32.
__global__ __launch_bounds__(256)
void mid(const float* __restrict__ zf, u16* __restrict__ Acat,
         const float* __restrict__ E, const float* __restrict__ Wpbf,
         u16* __restrict__ Wnb) {
    __shared__ float red[4];
    __shared__ float Es[32 * 16];
    const int bid = blockIdx.x, tid = threadIdx.x;
    if (bid < 2048) {
        const int n = bid, lane = tid & 63, wave = tid >> 6;
        const float* zr = zf + (size_t)n * 2048;
        float4 a = *(const float4*)(zr + tid * 8);
        float4 b = *(const float4*)(zr + tid * 8 + 4);
        float mx = fmaxf(fmaxf(fmaxf(a.x, a.y), fmaxf(a.z, a.w)),
                         fmaxf(fmaxf(b.x, b.y), fmaxf(b.z, b.w)));
        for (int off = 32; off; off >>= 1) mx = fmaxf(mx, __shfl_down(mx, off, 64));
        if (lane == 0) red[wave] = mx;
        __syncthreads();
        mx = fmaxf(fmaxf(red[0], red[1]), fmaxf(red[2], red[3]));
        __syncthreads();
        float v[8] = {__expf(a.x - mx), __expf(a.y - mx), __expf(a.z - mx), __expf(a.w - mx),
                      __expf(b.x - mx), __expf(b.y - mx), __expf(b.z - mx), __expf(b.w - mx)};
        float sum = v[0] + v[1] + v[2] + v[3] + v[4] + v[5] + v[6] + v[7];
        for (int off = 32; off; off >>= 1) sum += __shfl_down(sum, off, 64);
        if (lane == 0) red[wave] = sum;
        __syncthreads();
        sum = red[0] + red[1] + red[2] + red[3];
        float inv = 1.f / sum;
        u16* orow = Acat + (size_t)n * 4096 + tid * 8;
        *(ushort4*)orow = make_ushort4(f2bf(v[0] * inv), f2bf(v[1] * inv),
                                       f2bf(v[2] * inv), f2bf(v[3] * inv));
        *(ushort4*)(orow + 4) = make_ushort4(f2bf(v[4] * inv), f2bf(v[5] * inv),
                                             f2bf(v[6] * inv), f2bf(v[7] * inv));
    } else {
        const int w = bid - 2048;
        const int c0 = (w % 12) * 1024, n0 = (w / 12) * 32;
        for (int j = tid; j < 512; j += 256) Es[j] = E[(size_t)n0 * 16 + j];
        float4 wf[16];
#pragma unroll
        for (int d = 0; d < 16; ++d)
            wf[d] = *(const float4*)(Wpbf + (size_t)d * 12288 + c0 + tid * 4);
        __syncthreads();
        for (int nl = 0; nl < 32; ++nl) {
            float4 s = make_float4(0.f, 0.f, 0.f, 0.f);
#pragma unroll
            for (int d = 0; d < 16; ++d) {
                float e = Es[nl * 16 + d];
                s.x = fmaf(e, wf[d].x, s.x);
                s.y = fmaf(e, wf[d].y, s.y);
                s.z = fmaf(e, wf[d].z, s.z);
                s.w = fmaf(e, wf[d].w, s.w);
            }
            *(ushort4*)(Wnb + (size_t)(n0 + nl) * 12288 + c0 + tid * 4) =
                make_ushort4(f2bf(s.x), f2bf(s.y), f2bf(s.z), f2bf(s.w));
        }
    }
}

// ---------------------------------------------------------------- GEMM 128x128, BK=64, split-K
// Register-staged pipeline: tile k+1 global->VGPR before tile k's MFMAs; ds_write after.
__global__ __launch_bounds__(256, 3)
void gemm_bt(const u16* __restrict__ A, const u16* __restrict__ Bt,
             u16* __restrict__ Cp, int M, int N, int K, int Kh) {
    __shared__ alignas(16) u16 As[128 * 64];
    __shared__ alignas(16) u16 Bs[128 * 64];
    const int tid = threadIdx.x, lane = tid & 63, wave = tid >> 6;
    const int m0 = blockIdx.y * 128, n0 = blockIdx.x * 128;
    const int wm = (wave >> 1) * 64, wn = (wave & 1) * 64;
    const int kbeg = blockIdx.z * Kh, kend = kbeg + Kh;
    const int ml = lane & 15, c0l = lane >> 4;
    f32x4 acc[4][4] = {};

    // staging geometry (lane-linear slots, XOR-swizzled source chunk)
    int sIdx[4], rowI[4], gcI[4];
#pragma unroll
    for (int r = 0; r < 4; ++r) {
        int s = wave * 64 + r * 256 + lane;
        sIdx[r] = s; rowI[r] = s >> 3; gcI[r] = (s & 7) ^ ((s >> 3) & 7);
    }
    int baseA[4], mskA[4], baseB[4], mskB[4];
#pragma unroll
    for (int i = 0; i < 4; ++i) { int m = wm + i * 16 + ml; baseA[i] = m * 8; mskA[i] = m & 7; }
#pragma unroll
    for (int j = 0; j < 4; ++j) { int nn = wn + j * 16 + ml; baseB[j] = nn * 8; mskB[j] = nn & 7; }

    u16x8 ra[4], rb[4];
#pragma unroll
    for (int r = 0; r < 4; ++r) {
        ra[r] = *(const u16x8*)(A + (size_t)(m0 + rowI[r]) * K + kbeg + gcI[r] * 8);
        rb[r] = *(const u16x8*)(Bt + (size_t)(n0 + rowI[r]) * K + kbeg + gcI[r] * 8);
    }
#pragma unroll
    for (int r = 0; r < 4; ++r) {
        *(u16x8*)(As + (size_t)sIdx[r] * 8) = ra[r];
        *(u16x8*)(Bs + (size_t)sIdx[r] * 8) = rb[r];
    }
    __syncthreads();

    for (int k0 = kbeg; k0 < kend; k0 += 64) {
        const bool more = (k0 + 64) < kend;
        if (more) {                                  // prefetch next tile into regs
#pragma unroll
            for (int r = 0; r < 4; ++r) {
                ra[r] = *(const u16x8*)(A + (size_t)(m0 + rowI[r]) * K + (k0 + 64) + gcI[r] * 8);
                rb[r] = *(const u16x8*)(Bt + (size_t)(n0 + rowI[r]) * K + (k0 + 64) + gcI[r] * 8);
            }
        }
#pragma unroll
        for (int ks4 = 0; ks4 < 8; ks4 += 4) {       // 32 MFMAs over current LDS tile
            bf16x8 af[4], bv[4];
#pragma unroll
            for (int i = 0; i < 4; ++i)
                af[i] = *(const bf16x8*)(As + (baseA[i] + ((c0l + ks4) ^ mskA[i])) * 8);
#pragma unroll
            for (int j = 0; j < 4; ++j)
                bv[j] = *(const bf16x8*)(Bs + (baseB[j] + ((c0l + ks4) ^ mskB[j])) * 8);
#pragma unroll
            for (int i = 0; i < 4; ++i)
#pragma unroll
                for (int j = 0; j < 4; ++j)
                    acc[i][j] = __builtin_amdgcn_mfma_f32_16x16x32_bf16(af[i], bv[j], acc[i][j], 0, 0, 0);
        }
        if (more) {
            __syncthreads();                         // all waves done reading LDS
#pragma unroll
            for (int r = 0; r < 4; ++r) {
                *(u16x8*)(As + (size_t)sIdx[r] * 8) = ra[r];
                *(u16x8*)(Bs + (size_t)sIdx[r] * 8) = rb[r];
            }
            __syncthreads();                         // new tile visible
        }
    }

    const int col_l = lane & 15, row_l = (lane >> 4) * 4;
    u16* Cz = Cp + (size_t)blockIdx.z * M * N;
#pragma unroll
    for (int i = 0; i < 4; ++i)
#pragma unroll
        for (int j = 0; j < 4; ++j)
#pragma unroll
            for (int r = 0; r < 4; ++r) {
                int row = m0 + wm + i * 16 + row_l + r;
                int col = n0 + wn + j * 16 + col_l;
                Cz[(size_t)row * N + col] = f2bf(acc[i][j][r]);
            }
}

// ---------------------------------------------------------------- reduce_z
__global__ __launch_bounds__(256)
void reduce_z(const u16* __restrict__ p, const u16* __restrict__ Acat,
              u16* __restrict__ S) {
    size_t j = ((size_t)blockIdx.x * 256 + threadIdx.x) * 4;
    ushort4 p0 = *(const ushort4*)(p + j);
    ushort4 p1 = *(const ushort4*)(p + PSTRIDE + j);
    ushort4 p2 = *(const ushort4*)(p + 2 * PSTRIDE + j);
    ushort4 p3 = *(const ushort4*)(p + 3 * PSTRIDE + j);
    int row = (int)(j >> 11), col = (int)(j & 2047);
    ushort4 sp = *(const ushort4*)(Acat + (size_t)row * 4096 + col);
    ushort4 ad = *(const ushort4*)(Acat + (size_t)row * 4096 + 2048 + col);
    float z0 = bf2f(p0.x) + bf2f(p1.x) + bf2f(p2.x) + bf2f(p3.x);
    float z1 = bf2f(p0.y) + bf2f(p1.y) + bf2f(p2.y) + bf2f(p3.y);
    float z2 = bf2f(p0.z) + bf2f(p1.z) + bf2f(p2.z) + bf2f(p3.z);
    float z3 = bf2f(p0.w) + bf2f(p1.w) + bf2f(p2.w) + bf2f(p3.w);
    float s0 = 1.f / (1.f + __expf(-z0)), s1 = 1.f / (1.f + __expf(-z1));
    float s2 = 1.f / (1.f + __expf(-z2)), s3 = 1.f / (1.f + __expf(-z3));
    ushort4 o = make_ushort4(
        f2bf(s0 * bf2f(ad.x) + (1.f - s0) * bf2f(sp.x)),
        f2bf(s1 * bf2f(ad.y) + (1.f - s1) * bf2f(sp.y)),
        f2bf(s2 * bf2f(ad.z) + (1.f - s2) * bf2f(sp.z)),
        f2bf(s3 * bf2f(ad.w) + (1.f - s3) * bf2f(sp.w)));
    *(ushort4*)(S + j) = o;
}

// ---------------------------------------------------------------- reduceT
__global__ __launch_bounds__(256)
void reduceT(const u16* __restrict__ p, u16* __restrict__ xg1o,
             u16* __restrict__ xg1T, int mode) {
    __shared__ u16 t[64][68];
    int bx = blockIdx.x * 64, by = blockIdx.y * 64;
    int cg = threadIdx.x & 15, rg = threadIdx.x >> 4;
    int b = bx >> 6;
#pragma unroll
    for (int rr = 0; rr < 4; ++rr) {
        int row = rg * 4 + rr;
        size_t idx = (size_t)(by + row) * 2048 + bx + cg * 4;
        ushort4 q0 = *(const ushort4*)(p + idx);
        ushort4 q1 = *(const ushort4*)(p + PSTRIDE + idx);
        ushort4 q2 = *(const ushort4*)(p + 2 * PSTRIDE + idx);
        ushort4 q3 = *(const ushort4*)(p + 3 * PSTRIDE + idx);
        ushort4 v = make_ushort4(
            f2bf(bf2f(q0.x) + bf2f(q1.x) + bf2f(q2.x) + bf2f(q3.x)),
            f2bf(bf2f(q0.y) + bf2f(q1.y) + bf2f(q2.y) + bf2f(q3.y)),
            f2bf(bf2f(q0.z) + bf2f(q1.z) + bf2f(q2.z) + bf2f(q3.z)),
            f2bf(bf2f(q0.w) + bf2f(q1.w) + bf2f(q2.w) + bf2f(q3.w)));
        if (mode) *(ushort4*)(xg1o + idx) = v;
        else      *(ushort4*)(xg1o + ((size_t)b * 2048 + by + row) * 64 + cg * 4) = v;
        *(ushort4*)(&t[row][cg * 4]) = v;
    }
    __syncthreads();
    int c = threadIdx.x & 63, g = threadIdx.x >> 6;
#pragma unroll
    for (int r = 0; r < 16; ++r) {
        int row = g * 16 + r;
        xg1T[(size_t)(bx + row) * 2048 + by + c] = t[c][row];
    }
}

// ---------------------------------------------------------------- gconv_wn (Wn mode)
__global__ __launch_bounds__(256, 4)
void gconv_wn(const u16* __restrict__ xn, const u16* __restrict__ xg1n,
              const u16* __restrict__ p, const u16* __restrict__ Wnb,
              const float* __restrict__ bias, float* __restrict__ out) {
    __shared__ alignas(16) u16 As[32 * 192];
    __shared__ alignas(16) u16 Bs[64 * 192];
    const int n = blockIdx.x, tid = threadIdx.x;
    const int lane = tid & 63, wave = tid >> 6;
    const int wn2 = wave * 16;
    const int ml = lane & 15, c0l = lane >> 4;
    const int col = lane & 15, rl = (lane >> 4) * 4;

#pragma unroll
    for (int it = 0; it < 6; ++it) {
        int s = tid + it * 256;
        int row = s / 24, sc = s - row * 24;
        int gc = (sc & 24) | ((sc ^ row) & 7);
        gl_lds16(Wnb + (size_t)n * 12288 + (size_t)row * 192 + gc * 8, Bs + (size_t)s * 8);
    }
#pragma unroll
    for (int it = 0; it < 3; ++it) {
        int s = tid + it * 256;
        int row = s / 24, sc = s - row * 24;
        int gc = (sc & 24) | ((sc ^ row) & 7);
        u16x8 v;
        if (gc < 8) {
            v = *(const u16x8*)(xn + (size_t)n * 2048 + row * 64 + (gc & 7) * 8);
        } else if (gc < 16) {
            v = *(const u16x8*)(xg1n + (size_t)n * 2048 + row * 64 + (gc & 7) * 8);
        } else {
            const u16* pp = p + (size_t)n * 2048 + row * 64 + (gc & 7) * 8;
            u16x8 q0 = *(const u16x8*)pp;
            u16x8 q1 = *(const u16x8*)(pp + PSTRIDE);
            u16x8 q2 = *(const u16x8*)(pp + 2 * PSTRIDE);
            u16x8 q3 = *(const u16x8*)(pp + 3 * PSTRIDE);
#pragma unroll
            for (int tt = 0; tt < 8; ++tt)
                v[tt] = f2bf(bf2f(q0[tt]) + bf2f(q1[tt]) + bf2f(q2[tt]) + bf2f(q3[tt]));
        }
        *(u16x8*)(As + (size_t)s * 8) = v;
    }
    float bv0 = bias[(size_t)n * 64 + wn2 + col];
    f32x4 acc[2];
#pragma unroll
    for (int mt = 0; mt < 2; ++mt)
#pragma unroll
        for (int r = 0; r < 4; ++r) acc[mt][r] = bv0;
    __syncthreads();

#pragma unroll
    for (int ks = 0; ks < 6; ++ks) {
        int c = c0l + ks * 4;
        int o = wn2 + ml;
        bf16x8 bfrag = *(const bf16x8*)(Bs + (o * 24 + ((c & 24) | ((c ^ (o & 7)) & 7))) * 8);
#pragma unroll
        for (int mt = 0; mt < 2; ++mt) {
            int m = mt * 16 + ml;
            bf16x8 afrag = *(const bf16x8*)(As + (m * 24 + ((c & 24) | ((c ^ (m & 7)) & 7))) * 8);
            acc[mt] = __builtin_amdgcn_mfma_f32_16x16x32_bf16(afrag, bfrag, acc[mt], 0, 0, 0);
        }
    }
#pragma unroll
    for (int mt = 0; mt < 2; ++mt)
#pragma unroll
        for (int r = 0; r < 4; ++r) {
            int b = mt * 16 + rl + r;
            out[((size_t)b * 2048 + n) * 64 + wn2 + col] = acc[mt][r];
        }
}

// ---------------------------------------------------------------- gconv_mfma (legacy fallback)
__global__ __launch_bounds__(256, 2)
void gconv_mfma(const float* __restrict__ x, const u16* __restrict__ xg1,
                const u16* __restrict__ p, const u16* __restrict__ Wpb,
                const float* __restrict__ bias, const float* __restrict__ E,
                float* __restrict__ out) {
    __shared__ alignas(16) float El[16 * 128];
    const int tid = threadIdx.x, lane = tid & 63, wave = tid >> 6;
    const int m0 = blockIdx.x * 128, nb = m0 & 2047, bB = m0 >> 11;
    const int wm = (wave >> 1) * 64, wn = (wave & 1) * 32;
    const int ml = lane & 15, c0l = lane >> 4;
    const int col_l = lane & 15, rl = (lane >> 4) * 4;

#pragma unroll
    for (int it = 0; it < 8; ++it) {
        int idx = tid + it * 256;
        El[idx] = E[(size_t)(nb + (idx & 127)) * 16 + (idx >> 7)];
    }
    __syncthreads();

    bf16x8 af[4][6];
#pragma unroll
    for (int i = 0; i < 4; ++i) {
        const int row = m0 + wm + i * 16 + ml;
        const int n = row & 2047;
#pragma unroll
        for (int ks = 0; ks < 2; ++ks) {
            const float* xp = x + (size_t)row * 64 + (c0l + ks * 4) * 8;
            float4 a = *(const float4*)xp, b4 = *(const float4*)(xp + 4);
            u16x8 v;
            v[0] = f2bf(a.x);  v[1] = f2bf(a.y);  v[2] = f2bf(a.z);  v[3] = f2bf(a.w);
            v[4] = f2bf(b4.x); v[5] = f2bf(b4.y); v[6] = f2bf(b4.z); v[7] = f2bf(b4.w);
            af[i][ks] = __builtin_bit_cast(bf16x8, v);
        }
#pragma unroll
        for (int ks = 2; ks < 4; ++ks)
            af[i][ks] = *(const bf16x8*)(xg1 + (size_t)row * 64 + (c0l + ks * 4 - 8) * 8);
#pragma unroll
        for (int ks = 4; ks < 6; ++ks) {
            const u16* pp = p + (size_t)n * 2048 + bB * 64 + (c0l + ks * 4 - 16) * 8;
            u16x8 q0 = *(const u16x8*)pp;
            u16x8 q1 = *(const u16x8*)(pp + PSTRIDE);
            u16x8 q2 = *(const u16x8*)(pp + 2 * PSTRIDE);
            u16x8 q3 = *(const u16x8*)(pp + 3 * PSTRIDE);
            u16x8 v;
#pragma unroll
            for (int tt = 0; tt < 8; ++tt)
                v[tt] = f2bf(bf2f(q0[tt]) + bf2f(q1[tt]) + bf2f(q2[tt]) + bf2f(q3[tt]));
            af[i][ks] = __builtin_bit_cast(bf16x8, v);
        }
    }

    f32x4 oacc[4][2];
#pragma unroll
    for (int i = 0; i < 4; ++i)
#pragma unroll
        for (int j = 0; j < 2; ++j)
#pragma unroll
            for (int r = 0; r < 4; ++r)
                oacc[i][j][r] = bias[(size_t)(nb + wm + i * 16 + rl + r) * 64 + wn + j * 16 + col_l];

#pragma unroll 2
    for (int d = 0; d < 16; ++d) {
        bf16x8 bv[2][6];
#pragma unroll
        for (int j = 0; j < 2; ++j) {
            const u16* wp = Wpb + (size_t)(d * 64 + wn + j * 16 + ml) * 192 + c0l * 8;
#pragma unroll
            for (int ks = 0; ks < 6; ++ks)
                bv[j][ks] = *(const bf16x8*)(wp + ks * 32);
        }
        f32x4 tmp[4][2] = {};
#pragma unroll
        for (int ks = 0; ks < 6; ++ks)
#pragma unroll
            for (int i = 0; i < 4; ++i)
#pragma unroll
                for (int j = 0; j < 2; ++j)
                    tmp[i][j] = __builtin_amdgcn_mfma_f32_16x16x32_bf16(af[i][ks], bv[j][ks], tmp[i][j], 0, 0, 0);
#pragma unroll
        for (int i = 0; i < 4; ++i) {
            f32x4 ev = *(const f32x4*)(El + d * 128 + wm + i * 16 + rl);
#pragma unroll
            for (int r = 0; r < 4; ++r)
#pragma unroll
                for (int j = 0; j < 2; ++j)
                    oacc[i][j][r] = fmaf(ev[r], tmp[i][j][r], oacc[i][j][r]);
        }
    }
#pragma unroll
    for (int i = 0; i < 4; ++i)
#pragma unroll
        for (int j = 0; j < 2; ++j)
#pragma unroll
            for (int r = 0; r < 4; ++r)
                out[(size_t)(m0 + wm + i * 16 + rl + r) * 64 + wn + j * 16 + col_l] = oacc[i][j][r];
}

// ---------------------------------------------------------------- launch
extern "C" void kernel_launch(void* const* d_in, const int* in_sizes, int n_in,
                              void* d_out, int out_size, void* d_ws, size_t ws_size,
                              hipStream_t stream) {
    const float* x   = (const float*)d_in[0];
    const float* E   = (const float*)d_in[1];
    const float* adj = (const float*)d_in[2];
    const float* Wp  = (const float*)d_in[3];
    const float* bp  = (const float*)d_in[4];
    const float* saw = (const float*)d_in[5];
    float* out = (float*)d_out;

    char* ws = (char*)d_ws;
    const size_t MB = 1u << 20;
    const int wn_mode = (ws_size >= 140 * MB) ? 1 : 0;

    u16*   Acat  = (u16*)(ws);                  // [0,16M)
    u16*   sawb  = (u16*)(ws + 16 * MB);        // [16,32M)
    u16*   XtT   = (u16*)(ws + 32 * MB);        // [32,40M)
    u16*   Wpb   = (u16*)(ws + 40 * MB);        // [40,40.4M) bf16
    float* bias  = (float*)(ws + 41 * MB);      // [41,41.5M)
    float* Wpbf  = (float*)(ws + 42 * MB);      // [42,42.8M) fp32
    float* zf    = (float*)(ws + 48 * MB);      // [48,64M)
    u16*   part  = (u16*)(ws + 48 * MB);        // [48,80M)
    u16*   S_bf  = (u16*)(ws + 16 * MB);        // [16,24M)
    u16*   xg1T  = (u16*)(ws + 24 * MB);        // [24,32M)
    u16*   xg1o  = (u16*)(ws);                  // [0,8M)
    u16*   xn    = (u16*)(ws + 80 * MB);        // [80,88M)   wn only
    u16*   Wnb   = (u16*)(ws + 88 * MB);        // [88,138.4M) wn only

    preamble<<<13648, 256, 0, stream>>>(E, adj, saw, x, Wp, bp, zf, Acat, sawb, XtT,
                                        Wpb, Wpbf, bias, xn, wn_mode);
    mid<<<wn_mode ? 2816 : 2048, 256, 0, stream>>>(zf, Acat, E, Wpbf, Wnb);

    gemm_bt<<<dim3(16, 16, 4), 256, 0, stream>>>(Acat, sawb, part, 2048, 2048, 4096, 1024);
    reduce_z<<<4096, 256, 0, stream>>>(part, Acat, S_bf);
    gemm_bt<<<dim3(16, 16, 4), 256, 0, stream>>>(S_bf, XtT, part, 2048, 2048, 2048, 512);
    reduceT<<<dim3(32, 32), 256, 0, stream>>>(part, xg1o, xg1T, wn_mode);
    gemm_bt<<<dim3(16, 16, 4), 256, 0, stream>>>(S_bf, xg1T, part, 2048, 2048, 2048, 512);

    if (wn_mode)
        gconv_wn<<<2048, 256, 0, stream>>>(xn, xg1o, part, Wnb, bias, out);
    else
        gconv_mfma<<<512, 256, 0, stream>>>(x, xg1o, part, Wpb, bias, E, out);
}